// Round 15
// baseline (2046.566 us; speedup 1.0000x reference)
//
#include <hip/hip_runtime.h>
#include <hip/hip_bf16.h>
#include <math.h>

#define B_ 64
#define S_ 256
#define E_ 480
#define H_ 6
#define D_ 80
#define L_ 8
#define F_ 1920
#define CHORD_ 4576
#define TOKENS_ (B_*S_)
#define CROWS_ (B_*128)
#define QS_ 1440   // packed qkv row stride

typedef unsigned short u16;
typedef unsigned int u32;
typedef unsigned long long u64;
typedef __attribute__((ext_vector_type(8))) short short8;
typedef __attribute__((ext_vector_type(4))) float f32x4;
typedef __attribute__((ext_vector_type(4))) u32 u32x4;

__device__ __forceinline__ u16 f2bf(float f){
  u32 u = __float_as_uint(f);
  return (u16)((u + 0x7fffu + ((u >> 16) & 1u)) >> 16);
}

__device__ __forceinline__ void async_cp16(void* lds, const void* g){
  __builtin_amdgcn_global_load_lds((const __attribute__((address_space(1))) void*)g,
                                   (__attribute__((address_space(3))) void*)lds, 16, 0, 0);
}

// XCD-aware bijective block swizzle (m204)
__device__ __forceinline__ void xcd_tile(int gx, int gy, int& tx, int& ty){
  const int nwg = gx * gy;
  const int bid = blockIdx.y * gx + blockIdx.x;
  const int xcd = bid & 7, slot = bid >> 3;
  const int q8 = nwg >> 3, r8 = nwg & 7;
  const int t = slot + (xcd < r8 ? xcd * (q8 + 1) : r8 * (q8 + 1) + (xcd - r8) * q8);
  ty = t / gx;
  tx = t - ty * gx;
}

// ---------------- weight fp32 -> bf16 convert ----------------
__global__ void cvt_kernel(const float* __restrict__ s, u16* __restrict__ d, int n4)
{
  int i = blockIdx.x * 256 + threadIdx.x;
  const int stride = gridDim.x * 256;
  for (; i < n4; i += stride){
    float4 v = ((const float4*)s)[i];
    u64 w = (u64)((u32)f2bf(v.x) | ((u32)f2bf(v.y) << 16))
          | ((u64)((u32)f2bf(v.z) | ((u32)f2bf(v.w) << 16)) << 32);
    ((u64*)d)[i] = w;
  }
}

// pack Wq/Wk/Wv -> [L][3E][E] bf16
__global__ void qkv_cvt_kernel(const float* __restrict__ Wq, const float* __restrict__ Wk,
                               const float* __restrict__ Wv, u16* __restrict__ dst)
{
  const int per = E_*E_/4;
  const int tot = L_*3*per;
  int i = blockIdx.x * 256 + threadIdx.x;
  const int stride = gridDim.x * 256;
  for (; i < tot; i += stride){
    int l = i / (3*per);
    int rem = i - l*3*per;
    int sel = rem / per;
    int r2 = rem - sel*per;
    const float* src = (sel == 0) ? Wq : (sel == 1) ? Wk : Wv;
    float4 v = ((const float4*)(src + (size_t)l*E_*E_))[r2];
    u64 w = (u64)((u32)f2bf(v.x) | ((u32)f2bf(v.y) << 16))
          | ((u64)((u32)f2bf(v.z) | ((u32)f2bf(v.w) << 16)) << 32);
    ((u64*)dst)[i] = w;
  }
}

__global__ void bias_cat_kernel(const float* __restrict__ bq, const float* __restrict__ bk,
                                const float* __restrict__ bv, float* __restrict__ dst)
{
  int i = blockIdx.x * 256 + threadIdx.x;
  if (i >= L_*QS_) return;
  int l = i / QS_, c = i - l*QS_;
  float v = (c < 480) ? bq[l*480 + c] : (c < 960) ? bk[l*480 + c - 480] : bv[l*480 + c - 960];
  dst[i] = v;
}

// ---------------- embedding ----------------
__global__ void embed_kernel(const int* __restrict__ tok,
                             const float* __restrict__ tok_emb,
                             const float* __restrict__ pos_emb,
                             float* __restrict__ x)
{
  int row = blockIdx.x;
  int s = row & (S_-1);
  int t = tok[row];
  const float* te = tok_emb + (size_t)t * E_;
  const float* pe = pos_emb + (size_t)s * E_;
  float* xr = x + (size_t)row * E_;
  for (int e = threadIdx.x; e < E_; e += blockDim.x)
    xr[e] = te[e] + pe[e];
}

// ---------------- layernorm (fp32 in -> bf16 out) ----------------
__global__ __launch_bounds__(256) void ln_kernel(const float* __restrict__ x,
    const float* __restrict__ g, const float* __restrict__ b, u16* __restrict__ o)
{
  int wid = threadIdx.x >> 6, lane = threadIdx.x & 63;
  int row = blockIdx.x * 4 + wid;
  const float* xr = x + (size_t)row * E_;
  float v[8];
  #pragma unroll
  for (int i = 0; i < 7; ++i) v[i] = xr[lane + i*64];
  v[7] = (lane < 32) ? xr[448 + lane] : 0.f;
  float sum = 0.f, sq = 0.f;
  #pragma unroll
  for (int i = 0; i < 8; ++i){ sum += v[i]; sq += v[i]*v[i]; }
  #pragma unroll
  for (int m = 1; m < 64; m <<= 1){ sum += __shfl_xor(sum, m); sq += __shfl_xor(sq, m); }
  float mean = sum * (1.f/E_);
  float var  = sq  * (1.f/E_) - mean*mean;
  float rs = rsqrtf(var + 1e-5f);
  u16* orow = o + (size_t)row * E_;
  #pragma unroll
  for (int i = 0; i < 7; ++i){
    int idx = lane + i*64;
    orow[idx] = f2bf((v[i]-mean)*rs*g[idx] + b[idx]);
  }
  if (lane < 32){
    int idx = 448 + lane;
    orow[idx] = f2bf((v[7]-mean)*rs*g[idx] + b[idx]);
  }
}

// ---- 128x128 GEMM, bf16 weights, 2-phase, conflict-free LDS swizzle (round-9 proven) ----
// MODE 0: bf16 out;  1: bf16 out + exact GELU;  2: fp32 resid += ;  3: fp32 out
template<int MODE>
__global__ __launch_bounds__(256, 4) void gemm_bf_kernel(const u16* __restrict__ A,
                            const u16* __restrict__ Wb, const float* __restrict__ bias,
                            u16* __restrict__ Cb, float* __restrict__ Cf,
                            int M, int N, int K, int ldc)
{
  __shared__ u16 As[2][128*32];
  __shared__ u16 Ws[2][128*32];
  const int tid = threadIdx.x;
  const int wid = tid >> 6, lane = tid & 63;
  const int wr = wid >> 1, wc = wid & 1;
  const int lr = lane & 15, kg = lane >> 4;
  const int kgs = kg ^ ((lr >> 1) & 3);
  int tx, ty;
  xcd_tile(gridDim.x, gridDim.y, tx, ty);
  const int m0 = ty * 128;
  const int n0 = tx * 128;

  const f32x4 zero = {0.f,0.f,0.f,0.f};
  f32x4 acc[4][4];
  #pragma unroll
  for (int i=0;i<4;i++)
    #pragma unroll
    for (int j=0;j<4;j++)
      acc[i][j] = zero;

  const int srow = tid >> 2;
  const int schunk = (tid & 3) ^ ((srow >> 1) & 3);
  const u16* ap0 = A + (size_t)(m0 + srow) * K + schunk*8;
  const u16* ap1 = ap0 + (size_t)64 * K;
  int r0 = n0 + srow, r1 = r0 + 64;
  if (r0 >= N) r0 = N-1;
  if (r1 >= N) r1 = N-1;
  const u16* wp0 = Wb + (size_t)r0 * K + schunk*8;
  const u16* wp1 = Wb + (size_t)r1 * K + schunk*8;

  #define STAGE(bb, k0) do { \
    char* ab = (char*)As[bb] + wid*1024; \
    char* wb_ = (char*)Ws[bb] + wid*1024; \
    async_cp16(ab,        ap0 + (k0)); \
    async_cp16(ab + 4096, ap1 + (k0)); \
    async_cp16(wb_,        wp0 + (k0)); \
    async_cp16(wb_ + 4096, wp1 + (k0)); \
  } while(0)

  const int nsteps = K >> 5;
  STAGE(0, 0);
  __syncthreads();
  int cur = 0;
  for (int ks = 0; ks < nsteps; ++ks){
    if (ks + 1 < nsteps) STAGE(cur^1, (ks+1) << 5);

    short8 af[4], wf[4];
    #pragma unroll
    for (int i=0;i<4;i++) af[i] = *(const short8*)&As[cur][(wr*64 + i*16 + lr)*32 + kgs*8];
    #pragma unroll
    for (int j=0;j<4;j++) wf[j] = *(const short8*)&Ws[cur][(wc*64 + j*16 + lr)*32 + kgs*8];
    #pragma unroll
    for (int i=0;i<4;i++)
      #pragma unroll
      for (int j=0;j<4;j++)
        acc[i][j] = __builtin_amdgcn_mfma_f32_16x16x32_bf16(af[i], wf[j], acc[i][j], 0, 0, 0);

    __syncthreads();
    cur ^= 1;
  }
  #undef STAGE

  #pragma unroll
  for (int i=0;i<4;i++){
    const int row = m0 + wr*64 + i*16 + kg*4;
    #pragma unroll
    for (int j=0;j<4;j++){
      const int col = n0 + wc*64 + j*16 + lr;
      if (col < N){
        const float bv = bias[col];
        #pragma unroll
        for (int q=0;q<4;q++){
          float val = acc[i][j][q] + bv;
          size_t off = (size_t)(row + q) * ldc + col;
          if (MODE == 0){
            Cb[off] = f2bf(val);
          } else if (MODE == 1){
            float gx = 0.5f * val * (1.f + erff(val * 0.70710678118654752f));
            Cb[off] = f2bf(gx);
          } else if (MODE == 2){
            Cf[off] += val;
          } else {
            Cf[off] = val;
          }
        }
      }
    }
  }
}

// ---- 128x64 GEMM (BN=64), bf16 weights, same proven schedule/swizzle, 24 KB LDS ----
template<int MODE>
__global__ __launch_bounds__(256, 6) void gemm_bf64_kernel(const u16* __restrict__ A,
                            const u16* __restrict__ Wb, const float* __restrict__ bias,
                            u16* __restrict__ Cb, float* __restrict__ Cf,
                            int M, int N, int K, int ldc)
{
  __shared__ u16 As[2][128*32];   // 8 KB / buf
  __shared__ u16 Ws[2][64*32];    // 4 KB / buf
  const int tid = threadIdx.x;
  const int wid = tid >> 6, lane = tid & 63;
  const int wr = wid >> 1, wc = wid & 1;
  const int lr = lane & 15, kg = lane >> 4;
  const int kgs = kg ^ ((lr >> 1) & 3);
  int tx, ty;
  xcd_tile(gridDim.x, gridDim.y, tx, ty);
  const int m0 = ty * 128;
  const int n0 = tx * 64;

  const f32x4 zero = {0.f,0.f,0.f,0.f};
  f32x4 acc[4][2];
  #pragma unroll
  for (int i=0;i<4;i++)
    #pragma unroll
    for (int j=0;j<2;j++)
      acc[i][j] = zero;

  const int srow = tid >> 2;                          // 0..63
  const int schunk = (tid & 3) ^ ((srow >> 1) & 3);   // pre-swizzled source chunk
  const u16* ap0 = A + (size_t)(m0 + srow) * K + schunk*8;
  const u16* ap1 = ap0 + (size_t)64 * K;
  int r0 = n0 + srow;
  if (r0 >= N) r0 = N-1;
  const u16* wp0 = Wb + (size_t)r0 * K + schunk*8;

  #define STAGE(bb, k0) do { \
    char* ab = (char*)As[bb] + wid*1024; \
    char* wb_ = (char*)Ws[bb] + wid*1024; \
    async_cp16(ab,        ap0 + (k0)); \
    async_cp16(ab + 4096, ap1 + (k0)); \
    async_cp16(wb_,        wp0 + (k0)); \
  } while(0)

  const int nsteps = K >> 5;
  STAGE(0, 0);
  __syncthreads();
  int cur = 0;
  for (int ks = 0; ks < nsteps; ++ks){
    if (ks + 1 < nsteps) STAGE(cur^1, (ks+1) << 5);

    short8 af[4], wf[2];
    #pragma unroll
    for (int i=0;i<4;i++) af[i] = *(const short8*)&As[cur][(wr*64 + i*16 + lr)*32 + kgs*8];
    #pragma unroll
    for (int j=0;j<2;j++) wf[j] = *(const short8*)&Ws[cur][(wc*32 + j*16 + lr)*32 + kgs*8];
    #pragma unroll
    for (int i=0;i<4;i++)
      #pragma unroll
      for (int j=0;j<2;j++)
        acc[i][j] = __builtin_amdgcn_mfma_f32_16x16x32_bf16(af[i], wf[j], acc[i][j], 0, 0, 0);

    __syncthreads();
    cur ^= 1;
  }
  #undef STAGE

  #pragma unroll
  for (int i=0;i<4;i++){
    const int row = m0 + wr*64 + i*16 + kg*4;
    #pragma unroll
    for (int j=0;j<2;j++){
      const int col = n0 + wc*32 + j*16 + lr;
      if (col < N){
        const float bv = bias[col];
        #pragma unroll
        for (int q=0;q<4;q++){
          float val = acc[i][j][q] + bv;
          size_t off = (size_t)(row + q) * ldc + col;
          if (MODE == 0){
            Cb[off] = f2bf(val);
          } else if (MODE == 1){
            float gx = 0.5f * val * (1.f + erff(val * 0.70710678118654752f));
            Cb[off] = f2bf(gx);
          } else if (MODE == 2){
            Cf[off] += val;
          } else {
            Cf[off] = val;
          }
        }
      }
    }
  }
}

// ---------------- 128x128 GEMM, fp32 weights (fallback) ----------------
template<int MODE>
__global__ __launch_bounds__(256) void gemm_kernel(const u16* __restrict__ A, const float* __restrict__ W,
                            const float* __restrict__ bias,
                            u16* __restrict__ Cb, float* __restrict__ Cf,
                            int M, int N, int K, int ldc)
{
  __shared__ u16 As[128*32];
  __shared__ u16 Ws[128*32];
  const int tid = threadIdx.x;
  const int wid = tid >> 6, lane = tid & 63;
  const int wr = wid >> 1, wc = wid & 1;
  const int lr = lane & 15, kg = lane >> 4;
  int tx, ty;
  xcd_tile(gridDim.x, gridDim.y, tx, ty);
  const int m0 = ty * 128;
  const int n0 = tx * 128;

  const f32x4 zero = {0.f,0.f,0.f,0.f};
  f32x4 acc[4][4];
  #pragma unroll
  for (int i=0;i<4;i++)
    #pragma unroll
    for (int j=0;j<4;j++)
      acc[i][j] = zero;

  const int trow = tid >> 1;
  const int tcol = (tid & 1) * 16;
  const int wn = n0 + trow;
  const bool wok = wn < N;
  const float* wp = W + (size_t)wn * K + tcol;

  const u16* ap0 = A + (size_t)(m0 + (tid>>2)) * K + (tid&3)*8;
  const u16* ap1 = ap0 + (size_t)64 * K;
  char* lb0 = (char*)As + wid*1024;
  char* lb1 = (char*)As + 4096 + wid*1024;
  u32* wdst = (u32*)&Ws[trow*32 + tcol];

  const int nsteps = K >> 5;
  for (int ks = 0; ks < nsteps; ++ks){
    const int k0 = ks << 5;
    async_cp16(lb0, ap0 + k0);
    async_cp16(lb1, ap1 + k0);

    float wv[16];
    if (wok){
      const float4* s4 = (const float4*)(wp + k0);
      #pragma unroll
      for (int i=0;i<4;i++){
        float4 t4 = s4[i];
        wv[4*i]=t4.x; wv[4*i+1]=t4.y; wv[4*i+2]=t4.z; wv[4*i+3]=t4.w;
      }
    } else {
      #pragma unroll
      for (int i=0;i<16;i++) wv[i]=0.f;
    }
    u32 pk[8];
    #pragma unroll
    for (int i=0;i<8;i++) pk[i] = (u32)f2bf(wv[2*i]) | ((u32)f2bf(wv[2*i+1]) << 16);
    #pragma unroll
    for (int i=0;i<8;i++) wdst[i] = pk[i];

    __syncthreads();

    short8 af[4], wf[4];
    #pragma unroll
    for (int i=0;i<4;i++) af[i] = *(const short8*)&As[(wr*64 + i*16 + lr)*32 + kg*8];
    #pragma unroll
    for (int j=0;j<4;j++) wf[j] = *(const short8*)&Ws[(wc*64 + j*16 + lr)*32 + kg*8];
    #pragma unroll
    for (int i=0;i<4;i++)
      #pragma unroll
      for (int j=0;j<4;j++)
        acc[i][j] = __builtin_amdgcn_mfma_f32_16x16x32_bf16(af[i], wf[j], acc[i][j], 0, 0, 0);

    __syncthreads();
  }

  #pragma unroll
  for (int i=0;i<4;i++){
    const int row = m0 + wr*64 + i*16 + kg*4;
    #pragma unroll
    for (int j=0;j<4;j++){
      const int col = n0 + wc*64 + j*16 + lr;
      if (col < N){
        const float bv = bias[col];
        #pragma unroll
        for (int q=0;q<4;q++){
          float val = acc[i][j][q] + bv;
          size_t off = (size_t)(row + q) * ldc + col;
          if (MODE == 0){
            Cb[off] = f2bf(val);
          } else if (MODE == 1){
            float gx = 0.5f * val * (1.f + erff(val * 0.70710678118654752f));
            Cb[off] = f2bf(gx);
          } else if (MODE == 2){
            Cf[off] += val;
          } else {
            Cf[off] = val;
          }
        }
      }
    }
  }
}

// ---------------- MFMA flash attention, 16 waves/block (reads packed qkv) ----------------
#define KSTRIDE 104
#define VSTRIDE 264
__global__ __launch_bounds__(1024) void attn_mfma_kernel(const u16* __restrict__ QKV,
                                                         u16* __restrict__ O)
{
  __shared__ u16 ks[256*KSTRIDE];
  __shared__ u16 vt[80*VSTRIDE];
  const int bh = blockIdx.x;
  const int b = bh / H_, h = bh - b*H_;
  const int tid = threadIdx.x;
  const int wv = tid >> 6, lane = tid & 63;
  const int q16 = lane & 15, g = lane >> 4;

  if (tid < 512){           // stage K: 2 threads per row
    const int row = tid >> 1, half = tid & 1;
    const uint4* kr = (const uint4*)(QKV + (size_t)(b*S_ + row) * QS_ + h*D_ + 480);
    uint4 t0[5];
    #pragma unroll
    for (int i=0;i<5;i++) t0[i] = kr[half*5 + i];
    u16* krow = &ks[row*KSTRIDE];
    #pragma unroll
    for (int i=0;i<5;i++) *(uint4*)&krow[(half*5 + i)*8] = t0[i];
    if (half){
      const uint4 z4 = {0,0,0,0};
      *(uint4*)&krow[80] = z4;
      *(uint4*)&krow[88] = z4;
    }
  } else {                  // stage V transposed: 2 threads per row
    const int t = tid - 512, row = t >> 1, half = t & 1;
    const u32* vr = (const u32*)(QKV + (size_t)(b*S_ + row) * QS_ + h*D_ + 960);
    u32 t1[20];
    #pragma unroll
    for (int i=0;i<20;i++) t1[i] = vr[half*20 + i];
    #pragma unroll
    for (int i=0;i<20;i++){
      const int d = 2*(half*20 + i);
      vt[d*VSTRIDE + row]     = (u16)(t1[i] & 0xffffu);
      vt[(d+1)*VSTRIDE + row] = (u16)(t1[i] >> 16);
    }
  }
  const int qr = 16*wv;
  short8 bq0, bq1, bq2;
  {
    const short8 z8 = {0,0,0,0,0,0,0,0};
    const u16* qrow = QKV + (size_t)(b*S_ + qr + q16) * QS_ + h*D_;
    bq0 = *(const short8*)&qrow[g*8];
    bq1 = *(const short8*)&qrow[32 + g*8];
    bq2 = (g < 2) ? *(const short8*)&qrow[64 + g*8] : z8;
  }
  __syncthreads();

  f32x4 o_[5];
  #pragma unroll
  for (int j=0;j<5;j++) o_[j] = (f32x4){0.f,0.f,0.f,0.f};
  float m_ = -1e30f, l_ = 0.f;
  const float scale = 0.1118033988749895f;
  const int qglob = qr + q16;
  const int ktmax = (qr + 15) >> 5;

  for (int kt = 0; kt <= ktmax; ++kt){
    short8 af[2][3];
    #pragma unroll
    for (int a=0;a<2;a++)
      #pragma unroll
      for (int kk=0;kk<3;kk++)
        af[a][kk] = *(const short8*)&ks[(32*kt + 16*a + q16)*KSTRIDE + kk*32 + g*8];
    short8 bvv[5];
    #pragma unroll
    for (int j=0;j<5;j++)
      bvv[j] = *(const short8*)&vt[(16*j + q16)*VSTRIDE + kt*32 + g*8];

    f32x4 c0 = {0.f,0.f,0.f,0.f}, c1 = {0.f,0.f,0.f,0.f};
    c0 = __builtin_amdgcn_mfma_f32_16x16x32_bf16(af[0][0], bq0, c0, 0, 0, 0);
    c1 = __builtin_amdgcn_mfma_f32_16x16x32_bf16(af[1][0], bq0, c1, 0, 0, 0);
    c0 = __builtin_amdgcn_mfma_f32_16x16x32_bf16(af[0][1], bq1, c0, 0, 0, 0);
    c1 = __builtin_amdgcn_mfma_f32_16x16x32_bf16(af[1][1], bq1, c1, 0, 0, 0);
    c0 = __builtin_amdgcn_mfma_f32_16x16x32_bf16(af[0][2], bq2, c0, 0, 0, 0);
    c1 = __builtin_amdgcn_mfma_f32_16x16x32_bf16(af[1][2], bq2, c1, 0, 0, 0);

    const int kb0 = 32*kt + 4*g;
    const bool diag = (32*kt + 31) > qr;
    float s0[4], s1[4];
    #pragma unroll
    for (int r=0;r<4;r++){
      s0[r] = c0[r] * scale;
      s1[r] = c1[r] * scale;
      if (diag){
        if (kb0 + r > qglob)      s0[r] = -3e38f;
        if (kb0 + 16 + r > qglob) s1[r] = -3e38f;
      }
    }
    float mx = fmaxf(fmaxf(fmaxf(s0[0],s0[1]),fmaxf(s0[2],s0[3])),
                     fmaxf(fmaxf(s1[0],s1[1]),fmaxf(s1[2],s1[3])));
    mx = fmaxf(mx, __shfl_xor(mx, 16));
    mx = fmaxf(mx, __shfl_xor(mx, 32));
    const float mnew = fmaxf(m_, mx);
    const float resc = __expf(m_ - mnew);
    float p0[4], p1[4], ps = 0.f;
    #pragma unroll
    for (int r=0;r<4;r++){
      p0[r] = __expf(s0[r] - mnew);
      p1[r] = __expf(s1[r] - mnew);
      ps += p0[r] + p1[r];
    }
    ps += __shfl_xor(ps, 16);
    ps += __shfl_xor(ps, 32);
    l_ = l_ * resc + ps;
    m_ = mnew;
    float fr[4];
    #pragma unroll
    for (int r=0;r<4;r++) fr[r] = __shfl(resc, 4*g + r);
    #pragma unroll
    for (int j=0;j<5;j++){
      #pragma unroll
      for (int r=0;r<4;r++) o_[j][r] *= fr[r];
    }
    u32 pw0 = (u32)f2bf(p0[0]) | ((u32)f2bf(p0[1]) << 16);
    u32 pw1 = (u32)f2bf(p0[2]) | ((u32)f2bf(p0[3]) << 16);
    u32 pw2 = (u32)f2bf(p1[0]) | ((u32)f2bf(p1[1]) << 16);
    u32 pw3 = (u32)f2bf(p1[2]) | ((u32)f2bf(p1[3]) << 16);
    const int s01 = ((((g<<1)&3)<<4) + q16) << 2;
    const int s23 = (((((g<<1)+1)&3)<<4) + q16) << 2;
    int rA0 = __builtin_amdgcn_ds_bpermute(s01, (int)pw0);
    int rB0 = __builtin_amdgcn_ds_bpermute(s01, (int)pw2);
    int rA1 = __builtin_amdgcn_ds_bpermute(s01, (int)pw1);
    int rB1 = __builtin_amdgcn_ds_bpermute(s01, (int)pw3);
    int rA2 = __builtin_amdgcn_ds_bpermute(s23, (int)pw0);
    int rB2 = __builtin_amdgcn_ds_bpermute(s23, (int)pw2);
    int rA3 = __builtin_amdgcn_ds_bpermute(s23, (int)pw1);
    int rB3 = __builtin_amdgcn_ds_bpermute(s23, (int)pw3);
    const bool lo = (g < 2);
    u32x4 rw = { (u32)(lo ? rA0 : rB0), (u32)(lo ? rA1 : rB1),
                 (u32)(lo ? rA2 : rB2), (u32)(lo ? rA3 : rB3) };
    short8 pa = __builtin_bit_cast(short8, rw);
    #pragma unroll
    for (int j=0;j<5;j++)
      o_[j] = __builtin_amdgcn_mfma_f32_16x16x32_bf16(pa, bvv[j], o_[j], 0, 0, 0);
  }

  const float inv = 1.f / l_;
  float fr[4];
  #pragma unroll
  for (int r=0;r<4;r++) fr[r] = __shfl(inv, 4*g + r);
  #pragma unroll
  for (int j=0;j<5;j++){
    #pragma unroll
    for (int r=0;r<4;r++){
      const int row = qr + 4*g + r;
      O[(size_t)(b*S_ + row) * E_ + h*D_ + 16*j + q16] = f2bf(o_[j][r] * fr[r]);
    }
  }
}

// ---------------- gather odd positions -> bf16 ----------------
__global__ void gather_kernel(const float* __restrict__ x, u16* __restrict__ cin)
{
  int i = blockIdx.x * 256 + threadIdx.x;
  if (i >= CROWS_*E_) return;
  int row = i / E_, col = i - row*E_;
  int b = row >> 7, r = row & 127;
  cin[i] = f2bf(x[((size_t)(b*S_ + 2*r + 1))*E_ + col]);
}

extern "C" void kernel_launch(void* const* d_in, const int* in_sizes, int n_in,
                              void* d_out, int out_size, void* d_ws, size_t ws_size,
                              hipStream_t stream)
{
  (void)in_sizes; (void)n_in; (void)out_size;
  const int*   tok     = (const int*)d_in[0];
  const float* tok_emb = (const float*)d_in[1];
  const float* pos_emb = (const float*)d_in[2];
  const float* Wq = (const float*)d_in[3];
  const float* bq = (const float*)d_in[4];
  const float* Wk = (const float*)d_in[5];
  const float* bk = (const float*)d_in[6];
  const float* Wv = (const float*)d_in[7];
  const float* bv = (const float*)d_in[8];
  const float* Wo = (const float*)d_in[9];
  const float* bo = (const float*)d_in[10];
  const float* ln1s = (const float*)d_in[11];
  const float* ln1b = (const float*)d_in[12];
  const float* ln2s = (const float*)d_in[13];
  const float* ln2b = (const float*)d_in[14];
  const float* W1 = (const float*)d_in[15];
  const float* b1 = (const float*)d_in[16];
  const float* W2 = (const float*)d_in[17];
  const float* b2 = (const float*)d_in[18];
  const float* Wh = (const float*)d_in[19];
  const float* bh = (const float*)d_in[20];

  // ---- workspace layout (round-5/9 proven) ----
  char* p = (char*)d_ws;
  float* x  = (float*)p;            p += (size_t)TOKENS_*E_*4;
  u16* h    = (u16*)p;              p += (size_t)TOKENS_*E_*2;
  u16* qkv  = (u16*)p;
  u16* ao   = qkv + (size_t)TOKENS_*QS_;
  u16* ff1  = qkv;                   // aliases qkv+ao (dead by FFN time)
  u16* cin  = h;                     // aliases h (dead at gather time)
  p += (size_t)TOKENS_*QS_*2 + (size_t)TOKENS_*E_*2;

  const size_t szE  = (size_t)L_*E_*E_;
  const size_t szF  = (size_t)L_*F_*E_;
  const size_t szH  = (size_t)CHORD_*E_;
  u16* wqkv_bf = (u16*)p;            p += 3*szE*2;
  u16* wo_bf   = (u16*)p;            p += szE*2;
  u16* w1_bf   = (u16*)p;            p += szF*2;
  u16* w2_bf   = (u16*)p;            p += szF*2;
  u16* wh_bf   = (u16*)p;            p += szH*2;
  float* bqkv  = (float*)p;          p += (size_t)L_*QS_*4;
  const size_t need = (size_t)(p - (char*)d_ws);
  const bool bf16w = (ws_size >= need);

  embed_kernel<<<TOKENS_, 128, 0, stream>>>(tok, tok_emb, pos_emb, x);

  dim3 blk(256);
  dim3 gQKV64(23, TOKENS_/128);  // N=1440, BN=64 (ceil 1440/64=22.5 -> 23, ragged tile guarded)
  dim3 gE64(8, TOKENS_/128);     // N=480, BN=64
  dim3 gF164(30, TOKENS_/128);   // N=1920, BN=64
  dim3 gHd64(72, CROWS_/128);    // N=4576, BN=64 (71.5 -> 72, ragged guarded)

  if (bf16w){
    qkv_cvt_kernel<<<2048, blk, 0, stream>>>(Wq, Wk, Wv, wqkv_bf);
    bias_cat_kernel<<<(L_*QS_ + 255)/256, blk, 0, stream>>>(bq, bk, bv, bqkv);
    cvt_kernel<<<1024, blk, 0, stream>>>(Wo, wo_bf, (int)(szE/4));
    cvt_kernel<<<1024, blk, 0, stream>>>(W1, w1_bf, (int)(szF/4));
    cvt_kernel<<<1024, blk, 0, stream>>>(W2, w2_bf, (int)(szF/4));
    cvt_kernel<<<1024, blk, 0, stream>>>(Wh, wh_bf, (int)(szH/4));
    for (int i = 0; i < L_; ++i){
      ln_kernel<<<TOKENS_/4, blk, 0, stream>>>(x, ln1s + i*E_, ln1b + i*E_, h);
      gemm_bf64_kernel<0><<<gQKV64, blk, 0, stream>>>(h, wqkv_bf + (size_t)i*3*E_*E_, bqkv + i*QS_, qkv, nullptr, TOKENS_, QS_, E_, QS_);
      attn_mfma_kernel<<<B_*H_, dim3(1024), 0, stream>>>(qkv, ao);
      gemm_bf64_kernel<2><<<gE64, blk, 0, stream>>>(ao, wo_bf + (size_t)i*E_*E_, bo + i*E_, nullptr, x, TOKENS_, E_, E_, E_);
      ln_kernel<<<TOKENS_/4, blk, 0, stream>>>(x, ln2s + i*E_, ln2b + i*E_, h);
      gemm_bf64_kernel<1><<<gF164, blk, 0, stream>>>(h, w1_bf + (size_t)i*F_*E_, b1 + i*F_, ff1, nullptr, TOKENS_, F_, E_, F_);
      gemm_bf64_kernel<2><<<gE64, blk, 0, stream>>>(ff1, w2_bf + (size_t)i*E_*F_, b2 + i*E_, nullptr, x, TOKENS_, E_, F_, E_);
    }
    gather_kernel<<<(CROWS_*E_ + 255)/256, blk, 0, stream>>>(x, cin);
    gemm_bf64_kernel<3><<<gHd64, blk, 0, stream>>>(cin, wh_bf, bh, nullptr, (float*)d_out, CROWS_, CHORD_, E_, CHORD_);
  } else {
    for (int i = 0; i < L_; ++i){
      ln_kernel<<<TOKENS_/4, blk, 0, stream>>>(x, ln1s + i*E_, ln1b + i*E_, h);
      gemm_kernel<0><<<dim3(4, 128), blk, 0, stream>>>(h, Wq + (size_t)i*E_*E_, bq + i*E_, qkv, nullptr, TOKENS_, E_, E_, QS_);
      gemm_kernel<0><<<dim3(4, 128), blk, 0, stream>>>(h, Wk + (size_t)i*E_*E_, bk + i*E_, qkv + 480, nullptr, TOKENS_, E_, E_, QS_);
      gemm_kernel<0><<<dim3(4, 128), blk, 0, stream>>>(h, Wv + (size_t)i*E_*E_, bv + i*E_, qkv + 960, nullptr, TOKENS_, E_, E_, QS_);
      attn_mfma_kernel<<<B_*H_, dim3(1024), 0, stream>>>(qkv, ao);
      gemm_kernel<2><<<dim3(4, 128), blk, 0, stream>>>(ao, Wo + (size_t)i*E_*E_, bo + i*E_, nullptr, x, TOKENS_, E_, E_, E_);
      ln_kernel<<<TOKENS_/4, blk, 0, stream>>>(x, ln2s + i*E_, ln2b + i*E_, h);
      gemm_kernel<1><<<dim3(15, 128), blk, 0, stream>>>(h, W1 + (size_t)i*F_*E_, b1 + i*F_, ff1, nullptr, TOKENS_, F_, E_, F_);
      gemm_kernel<2><<<dim3(4, 128), blk, 0, stream>>>(ff1, W2 + (size_t)i*E_*F_, b2 + i*E_, nullptr, x, TOKENS_, E_, F_, E_);
    }
    gather_kernel<<<(CROWS_*E_ + 255)/256, blk, 0, stream>>>(x, cin);
    gemm_kernel<3><<<dim3(36, 64), blk, 0, stream>>>(cin, Wh, bh, nullptr, (float*)d_out, CROWS_, CHORD_, E_, CHORD_);
  }
}

// Round 16
// 1931.937 us; speedup vs baseline: 1.0593x; 1.0593x over previous
//
#include <hip/hip_runtime.h>
#include <hip/hip_bf16.h>
#include <math.h>

#define B_ 64
#define S_ 256
#define E_ 480
#define H_ 6
#define D_ 80
#define L_ 8
#define F_ 1920
#define CHORD_ 4576
#define TOKENS_ (B_*S_)
#define CROWS_ (B_*128)
#define QS_ 1440   // packed qkv row stride

typedef unsigned short u16;
typedef unsigned int u32;
typedef unsigned long long u64;
typedef __attribute__((ext_vector_type(8))) short short8;
typedef __attribute__((ext_vector_type(4))) float f32x4;
typedef __attribute__((ext_vector_type(4))) u32 u32x4;

__device__ __forceinline__ u16 f2bf(float f){
  u32 u = __float_as_uint(f);
  return (u16)((u + 0x7fffu + ((u >> 16) & 1u)) >> 16);
}

__device__ __forceinline__ void async_cp16(void* lds, const void* g){
  __builtin_amdgcn_global_load_lds((const __attribute__((address_space(1))) void*)g,
                                   (__attribute__((address_space(3))) void*)lds, 16, 0, 0);
}

// XCD-aware bijective block swizzle (m204)
__device__ __forceinline__ void xcd_tile(int gx, int gy, int& tx, int& ty){
  const int nwg = gx * gy;
  const int bid = blockIdx.y * gx + blockIdx.x;
  const int xcd = bid & 7, slot = bid >> 3;
  const int q8 = nwg >> 3, r8 = nwg & 7;
  const int t = slot + (xcd < r8 ? xcd * (q8 + 1) : r8 * (q8 + 1) + (xcd - r8) * q8);
  ty = t / gx;
  tx = t - ty * gx;
}

// ---------------- weight fp32 -> bf16 convert ----------------
__global__ void cvt_kernel(const float* __restrict__ s, u16* __restrict__ d, int n4)
{
  int i = blockIdx.x * 256 + threadIdx.x;
  const int stride = gridDim.x * 256;
  for (; i < n4; i += stride){
    float4 v = ((const float4*)s)[i];
    u64 w = (u64)((u32)f2bf(v.x) | ((u32)f2bf(v.y) << 16))
          | ((u64)((u32)f2bf(v.z) | ((u32)f2bf(v.w) << 16)) << 32);
    ((u64*)d)[i] = w;
  }
}

// pack Wq/Wk/Wv -> [L][3E][E] bf16
__global__ void qkv_cvt_kernel(const float* __restrict__ Wq, const float* __restrict__ Wk,
                               const float* __restrict__ Wv, u16* __restrict__ dst)
{
  const int per = E_*E_/4;
  const int tot = L_*3*per;
  int i = blockIdx.x * 256 + threadIdx.x;
  const int stride = gridDim.x * 256;
  for (; i < tot; i += stride){
    int l = i / (3*per);
    int rem = i - l*3*per;
    int sel = rem / per;
    int r2 = rem - sel*per;
    const float* src = (sel == 0) ? Wq : (sel == 1) ? Wk : Wv;
    float4 v = ((const float4*)(src + (size_t)l*E_*E_))[r2];
    u64 w = (u64)((u32)f2bf(v.x) | ((u32)f2bf(v.y) << 16))
          | ((u64)((u32)f2bf(v.z) | ((u32)f2bf(v.w) << 16)) << 32);
    ((u64*)dst)[i] = w;
  }
}

__global__ void bias_cat_kernel(const float* __restrict__ bq, const float* __restrict__ bk,
                                const float* __restrict__ bv, float* __restrict__ dst)
{
  int i = blockIdx.x * 256 + threadIdx.x;
  if (i >= L_*QS_) return;
  int l = i / QS_, c = i - l*QS_;
  float v = (c < 480) ? bq[l*480 + c] : (c < 960) ? bk[l*480 + c - 480] : bv[l*480 + c - 960];
  dst[i] = v;
}

// ---------------- embedding ----------------
__global__ void embed_kernel(const int* __restrict__ tok,
                             const float* __restrict__ tok_emb,
                             const float* __restrict__ pos_emb,
                             float* __restrict__ x)
{
  int row = blockIdx.x;
  int s = row & (S_-1);
  int t = tok[row];
  const float* te = tok_emb + (size_t)t * E_;
  const float* pe = pos_emb + (size_t)s * E_;
  float* xr = x + (size_t)row * E_;
  for (int e = threadIdx.x; e < E_; e += blockDim.x)
    xr[e] = te[e] + pe[e];
}

// ---------------- layernorm (fp32 in -> bf16 out) ----------------
__global__ __launch_bounds__(256) void ln_kernel(const float* __restrict__ x,
    const float* __restrict__ g, const float* __restrict__ b, u16* __restrict__ o)
{
  int wid = threadIdx.x >> 6, lane = threadIdx.x & 63;
  int row = blockIdx.x * 4 + wid;
  const float* xr = x + (size_t)row * E_;
  float v[8];
  #pragma unroll
  for (int i = 0; i < 7; ++i) v[i] = xr[lane + i*64];
  v[7] = (lane < 32) ? xr[448 + lane] : 0.f;
  float sum = 0.f, sq = 0.f;
  #pragma unroll
  for (int i = 0; i < 8; ++i){ sum += v[i]; sq += v[i]*v[i]; }
  #pragma unroll
  for (int m = 1; m < 64; m <<= 1){ sum += __shfl_xor(sum, m); sq += __shfl_xor(sq, m); }
  float mean = sum * (1.f/E_);
  float var  = sq  * (1.f/E_) - mean*mean;
  float rs = rsqrtf(var + 1e-5f);
  u16* orow = o + (size_t)row * E_;
  #pragma unroll
  for (int i = 0; i < 7; ++i){
    int idx = lane + i*64;
    orow[idx] = f2bf((v[i]-mean)*rs*g[idx] + b[idx]);
  }
  if (lane < 32){
    int idx = 448 + lane;
    orow[idx] = f2bf((v[7]-mean)*rs*g[idx] + b[idx]);
  }
}

// ---- 128x128 GEMM, bf16 weights, 2-phase, conflict-free LDS swizzle (round-9 proven) ----
// MODE 0: bf16 out;  1: bf16 out + exact GELU;  2: fp32 resid += ;  3: fp32 out
template<int MODE>
__global__ __launch_bounds__(256, 4) void gemm_bf_kernel(const u16* __restrict__ A,
                            const u16* __restrict__ Wb, const float* __restrict__ bias,
                            u16* __restrict__ Cb, float* __restrict__ Cf,
                            int M, int N, int K, int ldc)
{
  __shared__ u16 As[2][128*32];
  __shared__ u16 Ws[2][128*32];
  const int tid = threadIdx.x;
  const int wid = tid >> 6, lane = tid & 63;
  const int wr = wid >> 1, wc = wid & 1;
  const int lr = lane & 15, kg = lane >> 4;
  const int kgs = kg ^ ((lr >> 1) & 3);
  int tx, ty;
  xcd_tile(gridDim.x, gridDim.y, tx, ty);
  const int m0 = ty * 128;
  const int n0 = tx * 128;

  const f32x4 zero = {0.f,0.f,0.f,0.f};
  f32x4 acc[4][4];
  #pragma unroll
  for (int i=0;i<4;i++)
    #pragma unroll
    for (int j=0;j<4;j++)
      acc[i][j] = zero;

  const int srow = tid >> 2;
  const int schunk = (tid & 3) ^ ((srow >> 1) & 3);
  const u16* ap0 = A + (size_t)(m0 + srow) * K + schunk*8;
  const u16* ap1 = ap0 + (size_t)64 * K;
  int r0 = n0 + srow, r1 = r0 + 64;
  if (r0 >= N) r0 = N-1;
  if (r1 >= N) r1 = N-1;
  const u16* wp0 = Wb + (size_t)r0 * K + schunk*8;
  const u16* wp1 = Wb + (size_t)r1 * K + schunk*8;

  #define STAGE(bb, k0) do { \
    char* ab = (char*)As[bb] + wid*1024; \
    char* wb_ = (char*)Ws[bb] + wid*1024; \
    async_cp16(ab,        ap0 + (k0)); \
    async_cp16(ab + 4096, ap1 + (k0)); \
    async_cp16(wb_,        wp0 + (k0)); \
    async_cp16(wb_ + 4096, wp1 + (k0)); \
  } while(0)

  const int nsteps = K >> 5;
  STAGE(0, 0);
  __syncthreads();
  int cur = 0;
  for (int ks = 0; ks < nsteps; ++ks){
    if (ks + 1 < nsteps) STAGE(cur^1, (ks+1) << 5);

    short8 af[4], wf[4];
    #pragma unroll
    for (int i=0;i<4;i++) af[i] = *(const short8*)&As[cur][(wr*64 + i*16 + lr)*32 + kgs*8];
    #pragma unroll
    for (int j=0;j<4;j++) wf[j] = *(const short8*)&Ws[cur][(wc*64 + j*16 + lr)*32 + kgs*8];
    #pragma unroll
    for (int i=0;i<4;i++)
      #pragma unroll
      for (int j=0;j<4;j++)
        acc[i][j] = __builtin_amdgcn_mfma_f32_16x16x32_bf16(af[i], wf[j], acc[i][j], 0, 0, 0);

    __syncthreads();
    cur ^= 1;
  }
  #undef STAGE

  #pragma unroll
  for (int i=0;i<4;i++){
    const int row = m0 + wr*64 + i*16 + kg*4;
    #pragma unroll
    for (int j=0;j<4;j++){
      const int col = n0 + wc*64 + j*16 + lr;
      if (col < N){
        const float bv = bias[col];
        #pragma unroll
        for (int q=0;q<4;q++){
          float val = acc[i][j][q] + bv;
          size_t off = (size_t)(row + q) * ldc + col;
          if (MODE == 0){
            Cb[off] = f2bf(val);
          } else if (MODE == 1){
            float gx = 0.5f * val * (1.f + erff(val * 0.70710678118654752f));
            Cb[off] = f2bf(gx);
          } else if (MODE == 2){
            Cf[off] += val;
          } else {
            Cf[off] = val;
          }
        }
      }
    }
  }
}

// ---- 128x64 GEMM (BN=64), bf16 weights, same proven schedule/swizzle, 24 KB LDS ----
// For under-subscribed small-N GEMMs (Wo, W2): doubles block count -> more TLP.
template<int MODE>
__global__ __launch_bounds__(256, 6) void gemm_bf64_kernel(const u16* __restrict__ A,
                            const u16* __restrict__ Wb, const float* __restrict__ bias,
                            u16* __restrict__ Cb, float* __restrict__ Cf,
                            int M, int N, int K, int ldc)
{
  __shared__ u16 As[2][128*32];   // 8 KB / buf
  __shared__ u16 Ws[2][64*32];    // 4 KB / buf
  const int tid = threadIdx.x;
  const int wid = tid >> 6, lane = tid & 63;
  const int wr = wid >> 1, wc = wid & 1;
  const int lr = lane & 15, kg = lane >> 4;
  const int kgs = kg ^ ((lr >> 1) & 3);
  int tx, ty;
  xcd_tile(gridDim.x, gridDim.y, tx, ty);
  const int m0 = ty * 128;
  const int n0 = tx * 64;

  const f32x4 zero = {0.f,0.f,0.f,0.f};
  f32x4 acc[4][2];
  #pragma unroll
  for (int i=0;i<4;i++)
    #pragma unroll
    for (int j=0;j<2;j++)
      acc[i][j] = zero;

  const int srow = tid >> 2;                          // 0..63
  const int schunk = (tid & 3) ^ ((srow >> 1) & 3);   // pre-swizzled source chunk
  const u16* ap0 = A + (size_t)(m0 + srow) * K + schunk*8;
  const u16* ap1 = ap0 + (size_t)64 * K;
  int r0 = n0 + srow;
  if (r0 >= N) r0 = N-1;
  const u16* wp0 = Wb + (size_t)r0 * K + schunk*8;

  #define STAGE(bb, k0) do { \
    char* ab = (char*)As[bb] + wid*1024; \
    char* wb_ = (char*)Ws[bb] + wid*1024; \
    async_cp16(ab,        ap0 + (k0)); \
    async_cp16(ab + 4096, ap1 + (k0)); \
    async_cp16(wb_,        wp0 + (k0)); \
  } while(0)

  const int nsteps = K >> 5;
  STAGE(0, 0);
  __syncthreads();
  int cur = 0;
  for (int ks = 0; ks < nsteps; ++ks){
    if (ks + 1 < nsteps) STAGE(cur^1, (ks+1) << 5);

    short8 af[4], wf[2];
    #pragma unroll
    for (int i=0;i<4;i++) af[i] = *(const short8*)&As[cur][(wr*64 + i*16 + lr)*32 + kgs*8];
    #pragma unroll
    for (int j=0;j<2;j++) wf[j] = *(const short8*)&Ws[cur][(wc*32 + j*16 + lr)*32 + kgs*8];
    #pragma unroll
    for (int i=0;i<4;i++)
      #pragma unroll
      for (int j=0;j<2;j++)
        acc[i][j] = __builtin_amdgcn_mfma_f32_16x16x32_bf16(af[i], wf[j], acc[i][j], 0, 0, 0);

    __syncthreads();
    cur ^= 1;
  }
  #undef STAGE

  #pragma unroll
  for (int i=0;i<4;i++){
    const int row = m0 + wr*64 + i*16 + kg*4;
    #pragma unroll
    for (int j=0;j<2;j++){
      const int col = n0 + wc*32 + j*16 + lr;
      if (col < N){
        const float bv = bias[col];
        #pragma unroll
        for (int q=0;q<4;q++){
          float val = acc[i][j][q] + bv;
          size_t off = (size_t)(row + q) * ldc + col;
          if (MODE == 0){
            Cb[off] = f2bf(val);
          } else if (MODE == 1){
            float gx = 0.5f * val * (1.f + erff(val * 0.70710678118654752f));
            Cb[off] = f2bf(gx);
          } else if (MODE == 2){
            Cf[off] += val;
          } else {
            Cf[off] = val;
          }
        }
      }
    }
  }
}

// ---------------- 128x128 GEMM, fp32 weights (fallback) ----------------
template<int MODE>
__global__ __launch_bounds__(256) void gemm_kernel(const u16* __restrict__ A, const float* __restrict__ W,
                            const float* __restrict__ bias,
                            u16* __restrict__ Cb, float* __restrict__ Cf,
                            int M, int N, int K, int ldc)
{
  __shared__ u16 As[128*32];
  __shared__ u16 Ws[128*32];
  const int tid = threadIdx.x;
  const int wid = tid >> 6, lane = tid & 63;
  const int wr = wid >> 1, wc = wid & 1;
  const int lr = lane & 15, kg = lane >> 4;
  int tx, ty;
  xcd_tile(gridDim.x, gridDim.y, tx, ty);
  const int m0 = ty * 128;
  const int n0 = tx * 128;

  const f32x4 zero = {0.f,0.f,0.f,0.f};
  f32x4 acc[4][4];
  #pragma unroll
  for (int i=0;i<4;i++)
    #pragma unroll
    for (int j=0;j<4;j++)
      acc[i][j] = zero;

  const int trow = tid >> 1;
  const int tcol = (tid & 1) * 16;
  const int wn = n0 + trow;
  const bool wok = wn < N;
  const float* wp = W + (size_t)wn * K + tcol;

  const u16* ap0 = A + (size_t)(m0 + (tid>>2)) * K + (tid&3)*8;
  const u16* ap1 = ap0 + (size_t)64 * K;
  char* lb0 = (char*)As + wid*1024;
  char* lb1 = (char*)As + 4096 + wid*1024;
  u32* wdst = (u32*)&Ws[trow*32 + tcol];

  const int nsteps = K >> 5;
  for (int ks = 0; ks < nsteps; ++ks){
    const int k0 = ks << 5;
    async_cp16(lb0, ap0 + k0);
    async_cp16(lb1, ap1 + k0);

    float wv[16];
    if (wok){
      const float4* s4 = (const float4*)(wp + k0);
      #pragma unroll
      for (int i=0;i<4;i++){
        float4 t4 = s4[i];
        wv[4*i]=t4.x; wv[4*i+1]=t4.y; wv[4*i+2]=t4.z; wv[4*i+3]=t4.w;
      }
    } else {
      #pragma unroll
      for (int i=0;i<16;i++) wv[i]=0.f;
    }
    u32 pk[8];
    #pragma unroll
    for (int i=0;i<8;i++) pk[i] = (u32)f2bf(wv[2*i]) | ((u32)f2bf(wv[2*i+1]) << 16);
    #pragma unroll
    for (int i=0;i<8;i++) wdst[i] = pk[i];

    __syncthreads();

    short8 af[4], wf[4];
    #pragma unroll
    for (int i=0;i<4;i++) af[i] = *(const short8*)&As[(wr*64 + i*16 + lr)*32 + kg*8];
    #pragma unroll
    for (int j=0;j<4;j++) wf[j] = *(const short8*)&Ws[(wc*64 + j*16 + lr)*32 + kg*8];
    #pragma unroll
    for (int i=0;i<4;i++)
      #pragma unroll
      for (int j=0;j<4;j++)
        acc[i][j] = __builtin_amdgcn_mfma_f32_16x16x32_bf16(af[i], wf[j], acc[i][j], 0, 0, 0);

    __syncthreads();
  }

  #pragma unroll
  for (int i=0;i<4;i++){
    const int row = m0 + wr*64 + i*16 + kg*4;
    #pragma unroll
    for (int j=0;j<4;j++){
      const int col = n0 + wc*64 + j*16 + lr;
      if (col < N){
        const float bv = bias[col];
        #pragma unroll
        for (int q=0;q<4;q++){
          float val = acc[i][j][q] + bv;
          size_t off = (size_t)(row + q) * ldc + col;
          if (MODE == 0){
            Cb[off] = f2bf(val);
          } else if (MODE == 1){
            float gx = 0.5f * val * (1.f + erff(val * 0.70710678118654752f));
            Cb[off] = f2bf(gx);
          } else if (MODE == 2){
            Cf[off] += val;
          } else {
            Cf[off] = val;
          }
        }
      }
    }
  }
}

// ---------------- MFMA flash attention, 16 waves/block (reads packed qkv) ----------------
#define KSTRIDE 104
#define VSTRIDE 264
__global__ __launch_bounds__(1024) void attn_mfma_kernel(const u16* __restrict__ QKV,
                                                         u16* __restrict__ O)
{
  __shared__ u16 ks[256*KSTRIDE];
  __shared__ u16 vt[80*VSTRIDE];
  const int bh = blockIdx.x;
  const int b = bh / H_, h = bh - b*H_;
  const int tid = threadIdx.x;
  const int wv = tid >> 6, lane = tid & 63;
  const int q16 = lane & 15, g = lane >> 4;

  if (tid < 512){           // stage K: 2 threads per row
    const int row = tid >> 1, half = tid & 1;
    const uint4* kr = (const uint4*)(QKV + (size_t)(b*S_ + row) * QS_ + h*D_ + 480);
    uint4 t0[5];
    #pragma unroll
    for (int i=0;i<5;i++) t0[i] = kr[half*5 + i];
    u16* krow = &ks[row*KSTRIDE];
    #pragma unroll
    for (int i=0;i<5;i++) *(uint4*)&krow[(half*5 + i)*8] = t0[i];
    if (half){
      const uint4 z4 = {0,0,0,0};
      *(uint4*)&krow[80] = z4;
      *(uint4*)&krow[88] = z4;
    }
  } else {                  // stage V transposed: 2 threads per row
    const int t = tid - 512, row = t >> 1, half = t & 1;
    const u32* vr = (const u32*)(QKV + (size_t)(b*S_ + row) * QS_ + h*D_ + 960);
    u32 t1[20];
    #pragma unroll
    for (int i=0;i<20;i++) t1[i] = vr[half*20 + i];
    #pragma unroll
    for (int i=0;i<20;i++){
      const int d = 2*(half*20 + i);
      vt[d*VSTRIDE + row]     = (u16)(t1[i] & 0xffffu);
      vt[(d+1)*VSTRIDE + row] = (u16)(t1[i] >> 16);
    }
  }
  const int qr = 16*wv;
  short8 bq0, bq1, bq2;
  {
    const short8 z8 = {0,0,0,0,0,0,0,0};
    const u16* qrow = QKV + (size_t)(b*S_ + qr + q16) * QS_ + h*D_;
    bq0 = *(const short8*)&qrow[g*8];
    bq1 = *(const short8*)&qrow[32 + g*8];
    bq2 = (g < 2) ? *(const short8*)&qrow[64 + g*8] : z8;
  }
  __syncthreads();

  f32x4 o_[5];
  #pragma unroll
  for (int j=0;j<5;j++) o_[j] = (f32x4){0.f,0.f,0.f,0.f};
  float m_ = -1e30f, l_ = 0.f;
  const float scale = 0.1118033988749895f;
  const int qglob = qr + q16;
  const int ktmax = (qr + 15) >> 5;

  for (int kt = 0; kt <= ktmax; ++kt){
    short8 af[2][3];
    #pragma unroll
    for (int a=0;a<2;a++)
      #pragma unroll
      for (int kk=0;kk<3;kk++)
        af[a][kk] = *(const short8*)&ks[(32*kt + 16*a + q16)*KSTRIDE + kk*32 + g*8];
    short8 bvv[5];
    #pragma unroll
    for (int j=0;j<5;j++)
      bvv[j] = *(const short8*)&vt[(16*j + q16)*VSTRIDE + kt*32 + g*8];

    f32x4 c0 = {0.f,0.f,0.f,0.f}, c1 = {0.f,0.f,0.f,0.f};
    c0 = __builtin_amdgcn_mfma_f32_16x16x32_bf16(af[0][0], bq0, c0, 0, 0, 0);
    c1 = __builtin_amdgcn_mfma_f32_16x16x32_bf16(af[1][0], bq0, c1, 0, 0, 0);
    c0 = __builtin_amdgcn_mfma_f32_16x16x32_bf16(af[0][1], bq1, c0, 0, 0, 0);
    c1 = __builtin_amdgcn_mfma_f32_16x16x32_bf16(af[1][1], bq1, c1, 0, 0, 0);
    c0 = __builtin_amdgcn_mfma_f32_16x16x32_bf16(af[0][2], bq2, c0, 0, 0, 0);
    c1 = __builtin_amdgcn_mfma_f32_16x16x32_bf16(af[1][2], bq2, c1, 0, 0, 0);

    const int kb0 = 32*kt + 4*g;
    const bool diag = (32*kt + 31) > qr;
    float s0[4], s1[4];
    #pragma unroll
    for (int r=0;r<4;r++){
      s0[r] = c0[r] * scale;
      s1[r] = c1[r] * scale;
      if (diag){
        if (kb0 + r > qglob)      s0[r] = -3e38f;
        if (kb0 + 16 + r > qglob) s1[r] = -3e38f;
      }
    }
    float mx = fmaxf(fmaxf(fmaxf(s0[0],s0[1]),fmaxf(s0[2],s0[3])),
                     fmaxf(fmaxf(s1[0],s1[1]),fmaxf(s1[2],s1[3])));
    mx = fmaxf(mx, __shfl_xor(mx, 16));
    mx = fmaxf(mx, __shfl_xor(mx, 32));
    const float mnew = fmaxf(m_, mx);
    const float resc = __expf(m_ - mnew);
    float p0[4], p1[4], ps = 0.f;
    #pragma unroll
    for (int r=0;r<4;r++){
      p0[r] = __expf(s0[r] - mnew);
      p1[r] = __expf(s1[r] - mnew);
      ps += p0[r] + p1[r];
    }
    ps += __shfl_xor(ps, 16);
    ps += __shfl_xor(ps, 32);
    l_ = l_ * resc + ps;
    m_ = mnew;
    float fr[4];
    #pragma unroll
    for (int r=0;r<4;r++) fr[r] = __shfl(resc, 4*g + r);
    #pragma unroll
    for (int j=0;j<5;j++){
      #pragma unroll
      for (int r=0;r<4;r++) o_[j][r] *= fr[r];
    }
    u32 pw0 = (u32)f2bf(p0[0]) | ((u32)f2bf(p0[1]) << 16);
    u32 pw1 = (u32)f2bf(p0[2]) | ((u32)f2bf(p0[3]) << 16);
    u32 pw2 = (u32)f2bf(p1[0]) | ((u32)f2bf(p1[1]) << 16);
    u32 pw3 = (u32)f2bf(p1[2]) | ((u32)f2bf(p1[3]) << 16);
    const int s01 = ((((g<<1)&3)<<4) + q16) << 2;
    const int s23 = (((((g<<1)+1)&3)<<4) + q16) << 2;
    int rA0 = __builtin_amdgcn_ds_bpermute(s01, (int)pw0);
    int rB0 = __builtin_amdgcn_ds_bpermute(s01, (int)pw2);
    int rA1 = __builtin_amdgcn_ds_bpermute(s01, (int)pw1);
    int rB1 = __builtin_amdgcn_ds_bpermute(s01, (int)pw3);
    int rA2 = __builtin_amdgcn_ds_bpermute(s23, (int)pw0);
    int rB2 = __builtin_amdgcn_ds_bpermute(s23, (int)pw2);
    int rA3 = __builtin_amdgcn_ds_bpermute(s23, (int)pw1);
    int rB3 = __builtin_amdgcn_ds_bpermute(s23, (int)pw3);
    const bool lo = (g < 2);
    u32x4 rw = { (u32)(lo ? rA0 : rB0), (u32)(lo ? rA1 : rB1),
                 (u32)(lo ? rA2 : rB2), (u32)(lo ? rA3 : rB3) };
    short8 pa = __builtin_bit_cast(short8, rw);
    #pragma unroll
    for (int j=0;j<5;j++)
      o_[j] = __builtin_amdgcn_mfma_f32_16x16x32_bf16(pa, bvv[j], o_[j], 0, 0, 0);
  }

  const float inv = 1.f / l_;
  float fr[4];
  #pragma unroll
  for (int r=0;r<4;r++) fr[r] = __shfl(inv, 4*g + r);
  #pragma unroll
  for (int j=0;j<5;j++){
    #pragma unroll
    for (int r=0;r<4;r++){
      const int row = qr + 4*g + r;
      O[(size_t)(b*S_ + row) * E_ + h*D_ + 16*j + q16] = f2bf(o_[j][r] * fr[r]);
    }
  }
}

// ---------------- gather odd positions -> bf16 ----------------
__global__ void gather_kernel(const float* __restrict__ x, u16* __restrict__ cin)
{
  int i = blockIdx.x * 256 + threadIdx.x;
  if (i >= CROWS_*E_) return;
  int row = i / E_, col = i - row*E_;
  int b = row >> 7, r = row & 127;
  cin[i] = f2bf(x[((size_t)(b*S_ + 2*r + 1))*E_ + col]);
}

extern "C" void kernel_launch(void* const* d_in, const int* in_sizes, int n_in,
                              void* d_out, int out_size, void* d_ws, size_t ws_size,
                              hipStream_t stream)
{
  (void)in_sizes; (void)n_in; (void)out_size;
  const int*   tok     = (const int*)d_in[0];
  const float* tok_emb = (const float*)d_in[1];
  const float* pos_emb = (const float*)d_in[2];
  const float* Wq = (const float*)d_in[3];
  const float* bq = (const float*)d_in[4];
  const float* Wk = (const float*)d_in[5];
  const float* bk = (const float*)d_in[6];
  const float* Wv = (const float*)d_in[7];
  const float* bv = (const float*)d_in[8];
  const float* Wo = (const float*)d_in[9];
  const float* bo = (const float*)d_in[10];
  const float* ln1s = (const float*)d_in[11];
  const float* ln1b = (const float*)d_in[12];
  const float* ln2s = (const float*)d_in[13];
  const float* ln2b = (const float*)d_in[14];
  const float* W1 = (const float*)d_in[15];
  const float* b1 = (const float*)d_in[16];
  const float* W2 = (const float*)d_in[17];
  const float* b2 = (const float*)d_in[18];
  const float* Wh = (const float*)d_in[19];
  const float* bh = (const float*)d_in[20];

  // ---- workspace layout (round-5/9 proven) ----
  char* p = (char*)d_ws;
  float* x  = (float*)p;            p += (size_t)TOKENS_*E_*4;
  u16* h    = (u16*)p;              p += (size_t)TOKENS_*E_*2;
  u16* qkv  = (u16*)p;
  u16* ao   = qkv + (size_t)TOKENS_*QS_;
  u16* ff1  = qkv;                   // aliases qkv+ao (dead by FFN time)
  u16* cin  = h;                     // aliases h (dead at gather time)
  p += (size_t)TOKENS_*QS_*2 + (size_t)TOKENS_*E_*2;

  const size_t szE  = (size_t)L_*E_*E_;
  const size_t szF  = (size_t)L_*F_*E_;
  const size_t szH  = (size_t)CHORD_*E_;
  u16* wqkv_bf = (u16*)p;            p += 3*szE*2;
  u16* wo_bf   = (u16*)p;            p += szE*2;
  u16* w1_bf   = (u16*)p;            p += szF*2;
  u16* w2_bf   = (u16*)p;            p += szF*2;
  u16* wh_bf   = (u16*)p;            p += szH*2;
  float* bqkv  = (float*)p;          p += (size_t)L_*QS_*4;
  const size_t need = (size_t)(p - (char*)d_ws);
  const bool bf16w = (ws_size >= need);

  embed_kernel<<<TOKENS_, 128, 0, stream>>>(tok, tok_emb, pos_emb, x);

  dim3 blk(256);
  dim3 gQKV(12, TOKENS_/128);   // N=1440, BN=128 (oversubscribed -> keep wide)
  dim3 gE64(8, TOKENS_/128);    // N=480, BN=64 -> 1024 blocks (TLP win)
  dim3 gF1(15, TOKENS_/128);    // N=1920, BN=128
  dim3 gHd(36, CROWS_/128);     // N=4576, BN=128

  if (bf16w){
    qkv_cvt_kernel<<<2048, blk, 0, stream>>>(Wq, Wk, Wv, wqkv_bf);
    bias_cat_kernel<<<(L_*QS_ + 255)/256, blk, 0, stream>>>(bq, bk, bv, bqkv);
    cvt_kernel<<<1024, blk, 0, stream>>>(Wo, wo_bf, (int)(szE/4));
    cvt_kernel<<<1024, blk, 0, stream>>>(W1, w1_bf, (int)(szF/4));
    cvt_kernel<<<1024, blk, 0, stream>>>(W2, w2_bf, (int)(szF/4));
    cvt_kernel<<<1024, blk, 0, stream>>>(Wh, wh_bf, (int)(szH/4));
    for (int i = 0; i < L_; ++i){
      ln_kernel<<<TOKENS_/4, blk, 0, stream>>>(x, ln1s + i*E_, ln1b + i*E_, h);
      gemm_bf_kernel<0><<<gQKV, blk, 0, stream>>>(h, wqkv_bf + (size_t)i*3*E_*E_, bqkv + i*QS_, qkv, nullptr, TOKENS_, QS_, E_, QS_);
      attn_mfma_kernel<<<B_*H_, dim3(1024), 0, stream>>>(qkv, ao);
      gemm_bf64_kernel<2><<<gE64, blk, 0, stream>>>(ao, wo_bf + (size_t)i*E_*E_, bo + i*E_, nullptr, x, TOKENS_, E_, E_, E_);
      ln_kernel<<<TOKENS_/4, blk, 0, stream>>>(x, ln2s + i*E_, ln2b + i*E_, h);
      gemm_bf_kernel<1><<<gF1, blk, 0, stream>>>(h, w1_bf + (size_t)i*F_*E_, b1 + i*F_, ff1, nullptr, TOKENS_, F_, E_, F_);
      gemm_bf64_kernel<2><<<gE64, blk, 0, stream>>>(ff1, w2_bf + (size_t)i*E_*F_, b2 + i*E_, nullptr, x, TOKENS_, E_, F_, E_);
    }
    gather_kernel<<<(CROWS_*E_ + 255)/256, blk, 0, stream>>>(x, cin);
    gemm_bf_kernel<3><<<gHd, blk, 0, stream>>>(cin, wh_bf, bh, nullptr, (float*)d_out, CROWS_, CHORD_, E_, CHORD_);
  } else {
    for (int i = 0; i < L_; ++i){
      ln_kernel<<<TOKENS_/4, blk, 0, stream>>>(x, ln1s + i*E_, ln1b + i*E_, h);
      gemm_kernel<0><<<dim3(4, 128), blk, 0, stream>>>(h, Wq + (size_t)i*E_*E_, bq + i*E_, qkv, nullptr, TOKENS_, E_, E_, QS_);
      gemm_kernel<0><<<dim3(4, 128), blk, 0, stream>>>(h, Wk + (size_t)i*E_*E_, bk + i*E_, qkv + 480, nullptr, TOKENS_, E_, E_, QS_);
      gemm_kernel<0><<<dim3(4, 128), blk, 0, stream>>>(h, Wv + (size_t)i*E_*E_, bv + i*E_, qkv + 960, nullptr, TOKENS_, E_, E_, QS_);
      attn_mfma_kernel<<<B_*H_, dim3(1024), 0, stream>>>(qkv, ao);
      gemm_kernel<2><<<dim3(4, 128), blk, 0, stream>>>(ao, Wo + (size_t)i*E_*E_, bo + i*E_, nullptr, x, TOKENS_, E_, E_, E_);
      ln_kernel<<<TOKENS_/4, blk, 0, stream>>>(x, ln2s + i*E_, ln2b + i*E_, h);
      gemm_kernel<1><<<dim3(15, 128), blk, 0, stream>>>(h, W1 + (size_t)i*F_*E_, b1 + i*F_, ff1, nullptr, TOKENS_, F_, E_, F_);
      gemm_kernel<2><<<dim3(4, 128), blk, 0, stream>>>(ff1, W2 + (size_t)i*E_*F_, b2 + i*E_, nullptr, x, TOKENS_, E_, F_, E_);
    }
    gather_kernel<<<(CROWS_*E_ + 255)/256, blk, 0, stream>>>(x, cin);
    gemm_kernel<3><<<dim3(36, 64), blk, 0, stream>>>(cin, Wh, bh, nullptr, (float*)d_out, CROWS_, CHORD_, E_, CHORD_);
  }
}